// Round 2
// baseline (4151.522 us; speedup 1.0000x reference)
//
#include <hip/hip_runtime.h>
#include <hip/hip_bf16.h>

typedef __hip_bfloat16 bf16;

constexpr int NB  = 8;    // batch
constexpr int NHH = 128;  // H
constexpr int NWW = 128;  // W
constexpr int NE  = 192;  // E
constexpr int ND  = 576;  // D1 = 3E
constexpr int NR  = 512;  // RPE hidden
constexpr int NL  = 256;  // 2n
constexpr int NP  = NB * NHH * NWW;   // 131072 pixels total
constexpr int NPC = NHH * NWW;        // 16384 pixels per batch chunk

// ---------------- RPE coefficient nets ----------------
__global__ void k_rpe_pos(const float* __restrict__ pw1, const float* __restrict__ pb1,
                          const float* __restrict__ pw2, const float* __restrict__ pb2,
                          float* __restrict__ h)
{
    int net = blockIdx.x >> 8;
    int l   = blockIdx.x & 255;
    const float* pw = net ? pw2 : pw1;
    const float* pb = net ? pb2 : pb1;
    float idxv;
    if (l == 0 || l == 128) idxv = 0.f;
    else if (l < 128)       idxv = (float)l;
    else                    idxv = (float)(l - 256);
    float* hr = h + ((size_t)net * NL + l) * NR;
    for (int r = threadIdx.x; r < NR; r += 256)
        hr[r] = idxv * pw[r] + pb[r];
}

__global__ __launch_bounds__(256) void k_rpe_layer(
    const float* __restrict__ hin,
    const float* __restrict__ W1, const float* __restrict__ b1,
    const float* __restrict__ W2, const float* __restrict__ b2,
    float* __restrict__ out1, float* __restrict__ out2, int outdim)
{
    __shared__ float g[NR];
    __shared__ float red[256];
    int net = blockIdx.x >> 8;
    int l   = blockIdx.x & 255;
    const float* W  = net ? W2 : W1;
    const float* bb = net ? b2 : b1;
    const float* hr = hin + ((size_t)net * NL + l) * NR;
    int tid = threadIdx.x;
    float a0 = hr[tid], a1 = hr[tid + 256];
    red[tid] = a0 * a0 + a1 * a1;
    __syncthreads();
    for (int off = 128; off; off >>= 1) {
        if (tid < off) red[tid] += red[tid + off];
        __syncthreads();
    }
    float sc = 1.0f / (sqrtf(red[0]) * 0.044194173824159216f + 1e-8f);  // d=512
    g[tid]       = fmaxf(a0 * sc, 0.f);
    g[tid + 256] = fmaxf(a1 * sc, 0.f);
    __syncthreads();
    float* outr = (net ? out2 : out1) + (size_t)l * outdim;
    for (int j = tid; j < outdim; j += 256) {
        const float* wr = W + (size_t)j * NR;
        float acc = 0.f;
        #pragma unroll 8
        for (int r = 0; r < NR; ++r) acc += g[r] * wr[r];
        outr[j] = acc + bb[j];
    }
}

// ---------------- per-pixel srms scale (whole tensor) ----------------
__global__ void k_scale(const float* __restrict__ x, float* __restrict__ scale)
{
    int wave = (blockIdx.x * blockDim.x + threadIdx.x) >> 6;
    int lane = threadIdx.x & 63;
    int nw   = (gridDim.x * blockDim.x) >> 6;
    for (int p = wave; p < NP; p += nw) {
        const float* xp = x + (size_t)p * NE;
        float ss = 0.f;
        for (int k = lane; k < NE; k += 64) { float vv = xp[k]; ss += vv * vv; }
        for (int off = 32; off; off >>= 1) ss += __shfl_xor(ss, off, 64);
        if (lane == 0)
            scale[p] = 1.0f / (sqrtf(ss) * 0.07216878364870323f + 1e-8f);  // d=192
    }
}

// ---------------- u,v GEMM on one batch chunk ----------------
// grid (18, 256): N-tile 64 of 1152 (u|v), M-tile 64 pixels of 16384
__global__ __launch_bounds__(256) void k_uv(
    const float* __restrict__ x, const float* __restrict__ scale,
    const float* __restrict__ uw, const float* __restrict__ ub,
    const float* __restrict__ vw, const float* __restrict__ vb,
    bf16* __restrict__ u, bf16* __restrict__ v)
{
    __shared__ float xs[64][65];
    __shared__ float ws[64][65];
    int tid = threadIdx.x;
    int pbase = blockIdx.y * 64;
    int nbase = blockIdx.x * 64;
    int tx = tid & 15, ty = tid >> 4;
    float acc[4][4] = {};
    for (int kk = 0; kk < 3; ++kk) {
        #pragma unroll
        for (int i = 0; i < 16; ++i) {
            int idx = i * 256 + tid;
            int r = idx >> 6, k = idx & 63;
            xs[r][k] = x[(size_t)(pbase + r) * NE + kk * 64 + k] * scale[pbase + r];
            int jn = nbase + r;
            const float* Wr = (jn < ND) ? (uw + (size_t)jn * NE)
                                        : (vw + (size_t)(jn - ND) * NE);
            ws[r][k] = Wr[kk * 64 + k];
        }
        __syncthreads();
        #pragma unroll 4
        for (int k = 0; k < 64; ++k) {
            float av[4], bv[4];
            #pragma unroll
            for (int i = 0; i < 4; ++i) av[i] = xs[ty * 4 + i][k];
            #pragma unroll
            for (int j = 0; j < 4; ++j) bv[j] = ws[tx * 4 + j][k];
            #pragma unroll
            for (int i = 0; i < 4; ++i)
                #pragma unroll
                for (int j = 0; j < 4; ++j)
                    acc[i][j] += av[i] * bv[j];
        }
        __syncthreads();
    }
    #pragma unroll
    for (int i = 0; i < 4; ++i) {
        int p = pbase + ty * 4 + i;
        #pragma unroll
        for (int j = 0; j < 4; ++j) {
            int jn = nbase + tx * 4 + j;
            float bias = (jn < ND) ? ub[jn] : vb[jn - ND];
            float z = acc[i][j] + bias;
            float s = z / (1.f + __expf(-z));
            if (jn < ND) u[(size_t)p * ND + jn]        = __float2bfloat16(s);
            else         v[(size_t)p * ND + (jn - ND)] = __float2bfloat16(s);
        }
    }
}

// ---------------- Toeplitz conv along W (rpe1) on one chunk ----------------
// t[y,x,c] = sum_s A1[(x-s)&255][c] * v[y,s,c];  grid (18, 128)
__global__ __launch_bounds__(256) void k_conv_w(
    const bf16* __restrict__ v, const float* __restrict__ A1, bf16* __restrict__ t)
{
    __shared__ float vr[128][32];
    __shared__ float Al[256][32];
    int tid = threadIdx.x;
    int cc = blockIdx.x * 32;
    int y  = blockIdx.y;
    size_t rowbase = ((size_t)y * NWW) * ND + cc;
    #pragma unroll
    for (int i = 0; i < 16; ++i) {
        int idx = i * 256 + tid;
        int s = idx >> 5, c = idx & 31;
        vr[s][c] = __bfloat162float(v[rowbase + (size_t)s * ND + c]);
    }
    #pragma unroll
    for (int i = 0; i < 32; ++i) {
        int idx = i * 256 + tid;
        int k = idx >> 5, c = idx & 31;
        Al[k][c] = A1[(size_t)k * ND + cc + c];
    }
    __syncthreads();
    int c = tid & 31, xb = (tid >> 5) * 16;
    float acc[16] = {};
    for (int s = 0; s < 128; ++s) {
        float vv = vr[s][c];
        int kb = (xb - s) & 255;
        #pragma unroll
        for (int i = 0; i < 16; ++i)
            acc[i] += Al[(kb + i) & 255][c] * vv;
    }
    size_t obase = ((size_t)y * NWW + xb) * ND + cc + c;
    #pragma unroll
    for (int i = 0; i < 16; ++i)
        t[obase + (size_t)i * ND] = __float2bfloat16(acc[i]);
}

// ---------------- Toeplitz conv along H (rpe2) + combine, one chunk ----------------
// u[y,x,c] <- u[y,x,c] * ( t[y,x,c] + sum_s A2[(y-s)&255][c] * v[s,x,c] );  grid (18, 128)
__global__ __launch_bounds__(256) void k_conv_h(
    const bf16* __restrict__ v, const float* __restrict__ A2,
    const bf16* __restrict__ t, bf16* __restrict__ u)
{
    __shared__ float vc[128][32];
    __shared__ float Al[256][32];
    int tid = threadIdx.x;
    int cc = blockIdx.x * 32;
    int xx = blockIdx.y;
    #pragma unroll
    for (int i = 0; i < 16; ++i) {
        int idx = i * 256 + tid;
        int s = idx >> 5, c = idx & 31;
        vc[s][c] = __bfloat162float(v[((size_t)s * NWW + xx) * ND + cc + c]);
    }
    #pragma unroll
    for (int i = 0; i < 32; ++i) {
        int idx = i * 256 + tid;
        int k = idx >> 5, c = idx & 31;
        Al[k][c] = A2[(size_t)k * ND + cc + c];
    }
    __syncthreads();
    int c = tid & 31, yb = (tid >> 5) * 16;
    float acc[16] = {};
    for (int s = 0; s < 128; ++s) {
        float vv = vc[s][c];
        int kb = (yb - s) & 255;
        #pragma unroll
        for (int i = 0; i < 16; ++i)
            acc[i] += Al[(kb + i) & 255][c] * vv;
    }
    #pragma unroll
    for (int i = 0; i < 16; ++i) {
        size_t p = ((size_t)(yb + i) * NWW + xx) * ND + cc + c;
        float gv = __bfloat162float(u[p]) * (__bfloat162float(t[p]) + acc[i]);
        u[p] = __float2bfloat16(gv);
    }
}

// ---------------- final GEMM on one chunk: out = g @ o_w^T + o_b + x ----------------
// grid (3, 256)
__global__ __launch_bounds__(256) void k_out(
    const bf16* __restrict__ g, const float* __restrict__ ow, const float* __restrict__ ob,
    const float* __restrict__ x, float* __restrict__ out)
{
    __shared__ float gs[64][65];
    __shared__ float wsm[64][65];
    int tid = threadIdx.x;
    int pbase = blockIdx.y * 64;
    int nbase = blockIdx.x * 64;
    int tx = tid & 15, ty = tid >> 4;
    float acc[4][4] = {};
    for (int kk = 0; kk < 9; ++kk) {
        #pragma unroll
        for (int i = 0; i < 16; ++i) {
            int idx = i * 256 + tid;
            int r = idx >> 6, k = idx & 63;
            gs[r][k]  = __bfloat162float(g[(size_t)(pbase + r) * ND + kk * 64 + k]);
            wsm[r][k] = ow[(size_t)(nbase + r) * ND + kk * 64 + k];
        }
        __syncthreads();
        #pragma unroll 4
        for (int k = 0; k < 64; ++k) {
            float av[4], bv[4];
            #pragma unroll
            for (int i = 0; i < 4; ++i) av[i] = gs[ty * 4 + i][k];
            #pragma unroll
            for (int j = 0; j < 4; ++j) bv[j] = wsm[tx * 4 + j][k];
            #pragma unroll
            for (int i = 0; i < 4; ++i)
                #pragma unroll
                for (int j = 0; j < 4; ++j)
                    acc[i][j] += av[i] * bv[j];
        }
        __syncthreads();
    }
    #pragma unroll
    for (int i = 0; i < 4; ++i) {
        int p = pbase + ty * 4 + i;
        #pragma unroll
        for (int j = 0; j < 4; ++j) {
            int e = nbase + tx * 4 + j;
            out[(size_t)p * NE + e] = acc[i][j] + ob[e] + x[(size_t)p * NE + e];
        }
    }
}

extern "C" void kernel_launch(void* const* d_in, const int* in_sizes, int n_in,
                              void* d_out, int out_size, void* d_ws, size_t ws_size,
                              hipStream_t stream)
{
    const float* x    = (const float*)d_in[0];
    const float* u_w  = (const float*)d_in[1];
    const float* u_b  = (const float*)d_in[2];
    const float* v_w  = (const float*)d_in[3];
    const float* v_b  = (const float*)d_in[4];
    const float* o_w  = (const float*)d_in[5];
    const float* o_b  = (const float*)d_in[6];
    const float* r1_pw = (const float*)d_in[7];
    const float* r1_pb = (const float*)d_in[8];
    const float* r1_lw = (const float*)d_in[9];
    const float* r1_lb = (const float*)d_in[10];
    const float* r1_ow = (const float*)d_in[11];
    const float* r1_ob = (const float*)d_in[12];
    const float* r2_pw = (const float*)d_in[13];
    const float* r2_pb = (const float*)d_in[14];
    const float* r2_lw = (const float*)d_in[15];
    const float* r2_lb = (const float*)d_in[16];
    const float* r2_ow = (const float*)d_in[17];
    const float* r2_ob = (const float*)d_in[18];
    float* out = (float*)d_out;

    // workspace layout (~60 MB total)
    float* scale = (float*)d_ws;                       // NP floats
    float* A1 = scale + NP;                            // NL*ND
    float* A2 = A1 + (size_t)NL * ND;                  // NL*ND
    float* h0 = A2 + (size_t)NL * ND;                  // 2*NL*NR
    float* h1 = h0 + (size_t)2 * NL * NR;              // 2*NL*NR
    bf16* u = (bf16*)(h1 + (size_t)2 * NL * NR);       // NPC*ND bf16 (chunk)
    bf16* v = u + (size_t)NPC * ND;                    // NPC*ND bf16 (chunk)
    bf16* t = v + (size_t)NPC * ND;                    // NPC*ND bf16 (chunk)

    // RPE nets (both nets fused per launch; net = blockIdx>>8)
    k_rpe_pos<<<dim3(512), dim3(256), 0, stream>>>(r1_pw, r1_pb, r2_pw, r2_pb, h0);
    {
        const float* src[3] = { h0, h1, h0 };
        float* dst[3]       = { h1, h0, h1 };
        for (int i = 0; i < 3; ++i) {
            k_rpe_layer<<<dim3(512), dim3(256), 0, stream>>>(
                src[i], r1_lw + (size_t)i * NR * NR, r1_lb + (size_t)i * NR,
                        r2_lw + (size_t)i * NR * NR, r2_lb + (size_t)i * NR,
                dst[i], dst[i] + (size_t)NL * NR, NR);
        }
        // final: h1 -> A1 (rpe1, W axis), A2 (rpe2, H axis)
        k_rpe_layer<<<dim3(512), dim3(256), 0, stream>>>(
            h1, r1_ow, r1_ob, r2_ow, r2_ob, A1, A2, ND);
    }

    k_scale<<<dim3(2048), dim3(256), 0, stream>>>(x, scale);

    for (int b = 0; b < NB; ++b) {
        const float* xb = x + (size_t)b * NPC * NE;
        k_uv<<<dim3(18, 256), dim3(256), 0, stream>>>(
            xb, scale + (size_t)b * NPC, u_w, u_b, v_w, v_b, u, v);
        k_conv_w<<<dim3(18, 128), dim3(256), 0, stream>>>(v, A1, t);
        k_conv_h<<<dim3(18, 128), dim3(256), 0, stream>>>(v, A2, t, u);
        k_out<<<dim3(3, 256), dim3(256), 0, stream>>>(
            u, o_w, o_b, xb, out + (size_t)b * NPC * NE);
    }
}

// Round 3
// 1362.020 us; speedup vs baseline: 3.0481x; 3.0481x over previous
//
#include <hip/hip_runtime.h>
#include <hip/hip_bf16.h>

typedef __hip_bfloat16 bf16;
typedef __attribute__((ext_vector_type(4))) float f32x4;
typedef __attribute__((ext_vector_type(8))) __bf16 bf16x8;

constexpr int NB  = 8;    // batch
constexpr int NHH = 128;  // H
constexpr int NWW = 128;  // W
constexpr int NE  = 192;  // E
constexpr int ND  = 576;  // D1 = 3E
constexpr int NR  = 512;  // RPE hidden
constexpr int NL  = 256;  // 2n
constexpr int NP  = NB * NHH * NWW;   // 131072 pixels total
constexpr int NPC = NHH * NWW;        // 16384 pixels per batch chunk

__device__ __forceinline__ void gload16(const void* g, void* l) {
    __builtin_amdgcn_global_load_lds(
        (const __attribute__((address_space(1))) unsigned int*)g,
        (__attribute__((address_space(3))) unsigned int*)l, 16, 0, 0);
}

// ---------------- RPE coefficient nets ----------------
__global__ void k_rpe_pos(const float* __restrict__ pw1, const float* __restrict__ pb1,
                          const float* __restrict__ pw2, const float* __restrict__ pb2,
                          float* __restrict__ h)
{
    int net = blockIdx.x >> 8;
    int l   = blockIdx.x & 255;
    const float* pw = net ? pw2 : pw1;
    const float* pb = net ? pb2 : pb1;
    float idxv;
    if (l == 0 || l == 128) idxv = 0.f;
    else if (l < 128)       idxv = (float)l;
    else                    idxv = (float)(l - 256);
    float* hr = h + ((size_t)net * NL + l) * NR;
    for (int r = threadIdx.x; r < NR; r += 256)
        hr[r] = idxv * pw[r] + pb[r];
}

__global__ __launch_bounds__(256) void k_rpe_layer(
    const float* __restrict__ hin,
    const float* __restrict__ W1, const float* __restrict__ b1,
    const float* __restrict__ W2, const float* __restrict__ b2,
    float* __restrict__ out1, float* __restrict__ out2, int outdim)
{
    __shared__ float g[NR];
    __shared__ float red[256];
    int net = blockIdx.x >> 8;
    int l   = blockIdx.x & 255;
    const float* W  = net ? W2 : W1;
    const float* bb = net ? b2 : b1;
    const float* hr = hin + ((size_t)net * NL + l) * NR;
    int tid = threadIdx.x;
    float a0 = hr[tid], a1 = hr[tid + 256];
    red[tid] = a0 * a0 + a1 * a1;
    __syncthreads();
    for (int off = 128; off; off >>= 1) {
        if (tid < off) red[tid] += red[tid + off];
        __syncthreads();
    }
    float sc = 1.0f / (sqrtf(red[0]) * 0.044194173824159216f + 1e-8f);  // d=512
    g[tid]       = fmaxf(a0 * sc, 0.f);
    g[tid + 256] = fmaxf(a1 * sc, 0.f);
    __syncthreads();
    float* outr = (net ? out2 : out1) + (size_t)l * outdim;
    for (int j = tid; j < outdim; j += 256) {
        const float* wr = W + (size_t)j * NR;
        float acc = 0.f;
        #pragma unroll 8
        for (int r = 0; r < NR; ++r) acc += g[r] * wr[r];
        outr[j] = acc + bb[j];
    }
}

// ---------------- fused srms + bf16 cast for one chunk ----------------
// wave per pixel; grid 4096 x 256
__global__ void k_prep(const float* __restrict__ x, bf16* __restrict__ xb)
{
    int p = blockIdx.x * 4 + (threadIdx.x >> 6);
    int lane = threadIdx.x & 63;
    const float* xp = x + (size_t)p * NE;
    float v0 = xp[lane], v1 = xp[lane + 64], v2 = xp[lane + 128];
    float ss = v0 * v0 + v1 * v1 + v2 * v2;
    for (int off = 32; off; off >>= 1) ss += __shfl_xor(ss, off, 64);
    float sc = 1.0f / (sqrtf(ss) * 0.07216878364870323f + 1e-8f);  // d=192
    bf16* op = xb + (size_t)p * NE;
    op[lane]       = __float2bfloat16(v0 * sc);
    op[lane + 64]  = __float2bfloat16(v1 * sc);
    op[lane + 128] = __float2bfloat16(v2 * sc);
}

// ---------------- one-time weight bf16 conversion ----------------
// wb[1152][192] = [uw; vw]; owb[192][576] = ow.  grid 1296 x 256 (exact)
__global__ void k_wconv(const float* __restrict__ uw, const float* __restrict__ vw,
                        const float* __restrict__ ow,
                        bf16* __restrict__ wb, bf16* __restrict__ owb)
{
    int i = blockIdx.x * 256 + threadIdx.x;
    constexpr int S = ND * NE;  // 110592
    if (i < S)          wb[i]  = __float2bfloat16(uw[i]);
    else if (i < 2 * S) wb[i]  = __float2bfloat16(vw[i - S]);
    else                owb[i - 2 * S] = __float2bfloat16(ow[i - 2 * S]);
}

// ---------------- u,v MFMA GEMM on one chunk ----------------
// C[p][jn] = silu( sum_k xb[p][k] * wb[jn][k] + bias[jn] ), M=16384 N=1152 K=192
// tile 128x128, BK=64, 4 waves (2x2), wave tile 64x64. grid (9, 128)
__global__ __launch_bounds__(256) void k_uv(
    const bf16* __restrict__ xb, const bf16* __restrict__ wb,
    const float* __restrict__ ub, const float* __restrict__ vb,
    bf16* __restrict__ u, bf16* __restrict__ v)
{
    __shared__ bf16 sA[128][64];
    __shared__ bf16 sB[128][64];
    int tid = threadIdx.x;
    int wv = tid >> 6, lane = tid & 63;
    int pbase = blockIdx.y * 128;
    int nbase = blockIdx.x * 128;
    int wr = wv >> 1, wc = wv & 1;
    int lrow = lane >> 3, lcol = lane & 7;
    f32x4 acc[4][4] = {};
    for (int kk = 0; kk < 3; ++kk) {
        #pragma unroll
        for (int i = 0; i < 4; ++i) {
            int row = wv * 32 + i * 8;
            gload16((const char*)(xb + (size_t)(pbase + row + lrow) * NE + kk * 64) + lcol * 16,
                    &sA[row][0]);
            gload16((const char*)(wb + (size_t)(nbase + row + lrow) * NE + kk * 64) + lcol * 16,
                    &sB[row][0]);
        }
        asm volatile("s_waitcnt vmcnt(0)" ::: "memory");
        __syncthreads();
        #pragma unroll
        for (int k2 = 0; k2 < 2; ++k2) {
            bf16x8 af[4], bw[4];
            #pragma unroll
            for (int m = 0; m < 4; ++m)
                af[m] = *(const bf16x8*)&sA[wr * 64 + m * 16 + (lane & 15)][k2 * 32 + (lane >> 4) * 8];
            #pragma unroll
            for (int n = 0; n < 4; ++n)
                bw[n] = *(const bf16x8*)&sB[wc * 64 + n * 16 + (lane & 15)][k2 * 32 + (lane >> 4) * 8];
            #pragma unroll
            for (int m = 0; m < 4; ++m)
                #pragma unroll
                for (int n = 0; n < 4; ++n)
                    acc[m][n] = __builtin_amdgcn_mfma_f32_16x16x32_bf16(af[m], bw[n], acc[m][n], 0, 0, 0);
        }
        __syncthreads();
    }
    int fr = lane & 15, fq = lane >> 4;
    #pragma unroll
    for (int m = 0; m < 4; ++m) {
        #pragma unroll
        for (int n = 0; n < 4; ++n) {
            int jn = nbase + wc * 64 + n * 16 + fr;
            float bias = (jn < ND) ? ub[jn] : vb[jn - ND];
            #pragma unroll
            for (int j = 0; j < 4; ++j) {
                int p = pbase + wr * 64 + m * 16 + fq * 4 + j;
                float z = acc[m][n][j] + bias;
                float s = z / (1.f + __expf(-z));
                if (jn < ND) u[(size_t)p * ND + jn]        = __float2bfloat16(s);
                else         v[(size_t)p * ND + (jn - ND)] = __float2bfloat16(s);
            }
        }
    }
}

// ---------------- Toeplitz conv along W (rpe1), register-window ----------------
// t[y,x,c] = sum_s A1[(x-s)&255][c] * v[y,s,c];  grid (18, 128)
__global__ __launch_bounds__(256) void k_conv_w(
    const bf16* __restrict__ v, const float* __restrict__ A1, bf16* __restrict__ t)
{
    __shared__ float vr[128][32];
    __shared__ float Al[256][32];
    int tid = threadIdx.x;
    int cc = blockIdx.x * 32;
    int y  = blockIdx.y;
    size_t rowbase = ((size_t)y * NWW) * ND + cc;
    #pragma unroll
    for (int i = 0; i < 16; ++i) {
        int idx = i * 256 + tid;
        int s = idx >> 5, c = idx & 31;
        vr[s][c] = __bfloat162float(v[rowbase + (size_t)s * ND + c]);
    }
    #pragma unroll
    for (int i = 0; i < 32; ++i) {
        int idx = i * 256 + tid;
        int k = idx >> 5, c = idx & 31;
        Al[k][c] = A1[(size_t)k * ND + cc + c];
    }
    __syncthreads();
    int c = tid & 31, xb = (tid >> 5) * 16;
    float acc[16] = {};
    float wA[16];
    #pragma unroll
    for (int i = 0; i < 16; ++i) wA[i] = Al[(xb + i) & 255][c];
    for (int s8 = 0; s8 < 8; ++s8) {
        #pragma unroll
        for (int ss = 0; ss < 16; ++ss) {
            int s = s8 * 16 + ss;
            float vv = vr[s][c];
            #pragma unroll
            for (int i = 0; i < 16; ++i)
                acc[i] += wA[(i - ss) & 15] * vv;   // wA_log[i] = A1[(xb+i-s)&255][c]
            wA[(-(ss + 1)) & 15] = Al[(xb - s - 1) & 255][c];
        }
    }
    size_t obase = ((size_t)y * NWW + xb) * ND + cc + c;
    #pragma unroll
    for (int i = 0; i < 16; ++i)
        t[obase + (size_t)i * ND] = __float2bfloat16(acc[i]);
}

// ---------------- Toeplitz conv along H (rpe2) + combine ----------------
// u[y,x,c] <- u * ( t + sum_s A2[(y-s)&255][c] * v[s,x,c] );  grid (18, 128)
__global__ __launch_bounds__(256) void k_conv_h(
    const bf16* __restrict__ v, const float* __restrict__ A2,
    const bf16* __restrict__ t, bf16* __restrict__ u)
{
    __shared__ float vc[128][32];
    __shared__ float Al[256][32];
    int tid = threadIdx.x;
    int cc = blockIdx.x * 32;
    int xx = blockIdx.y;
    #pragma unroll
    for (int i = 0; i < 16; ++i) {
        int idx = i * 256 + tid;
        int s = idx >> 5, c = idx & 31;
        vc[s][c] = __bfloat162float(v[((size_t)s * NWW + xx) * ND + cc + c]);
    }
    #pragma unroll
    for (int i = 0; i < 32; ++i) {
        int idx = i * 256 + tid;
        int k = idx >> 5, c = idx & 31;
        Al[k][c] = A2[(size_t)k * ND + cc + c];
    }
    __syncthreads();
    int c = tid & 31, yb = (tid >> 5) * 16;
    float acc[16] = {};
    float wA[16];
    #pragma unroll
    for (int i = 0; i < 16; ++i) wA[i] = Al[(yb + i) & 255][c];
    for (int s8 = 0; s8 < 8; ++s8) {
        #pragma unroll
        for (int ss = 0; ss < 16; ++ss) {
            int s = s8 * 16 + ss;
            float vv = vc[s][c];
            #pragma unroll
            for (int i = 0; i < 16; ++i)
                acc[i] += wA[(i - ss) & 15] * vv;
            wA[(-(ss + 1)) & 15] = Al[(yb - s - 1) & 255][c];
        }
    }
    #pragma unroll
    for (int i = 0; i < 16; ++i) {
        size_t p = ((size_t)(yb + i) * NWW + xx) * ND + cc + c;
        float gv = __bfloat162float(u[p]) * (__bfloat162float(t[p]) + acc[i]);
        u[p] = __float2bfloat16(gv);
    }
}

// ---------------- final MFMA GEMM: out = g @ owb^T + ob + x ----------------
// M=16384 N=192 K=576; tile 128x64, BK=64, 4 waves (2x2), wave tile 64x32. grid (3, 128)
__global__ __launch_bounds__(256) void k_out(
    const bf16* __restrict__ g, const bf16* __restrict__ owb,
    const float* __restrict__ ob, const float* __restrict__ x, float* __restrict__ out)
{
    __shared__ bf16 sA[128][64];
    __shared__ bf16 sB[64][64];
    int tid = threadIdx.x;
    int wv = tid >> 6, lane = tid & 63;
    int pbase = blockIdx.y * 128;
    int nbase = blockIdx.x * 64;
    int wr = wv >> 1, wc = wv & 1;
    int lrow = lane >> 3, lcol = lane & 7;
    f32x4 acc[4][2] = {};
    for (int kk = 0; kk < 9; ++kk) {
        #pragma unroll
        for (int i = 0; i < 4; ++i) {
            int row = wv * 32 + i * 8;
            gload16((const char*)(g + (size_t)(pbase + row + lrow) * ND + kk * 64) + lcol * 16,
                    &sA[row][0]);
        }
        #pragma unroll
        for (int i = 0; i < 2; ++i) {
            int row = wv * 16 + i * 8;
            gload16((const char*)(owb + (size_t)(nbase + row + lrow) * ND + kk * 64) + lcol * 16,
                    &sB[row][0]);
        }
        asm volatile("s_waitcnt vmcnt(0)" ::: "memory");
        __syncthreads();
        #pragma unroll
        for (int k2 = 0; k2 < 2; ++k2) {
            bf16x8 af[4], bw[2];
            #pragma unroll
            for (int m = 0; m < 4; ++m)
                af[m] = *(const bf16x8*)&sA[wr * 64 + m * 16 + (lane & 15)][k2 * 32 + (lane >> 4) * 8];
            #pragma unroll
            for (int n = 0; n < 2; ++n)
                bw[n] = *(const bf16x8*)&sB[wc * 32 + n * 16 + (lane & 15)][k2 * 32 + (lane >> 4) * 8];
            #pragma unroll
            for (int m = 0; m < 4; ++m)
                #pragma unroll
                for (int n = 0; n < 2; ++n)
                    acc[m][n] = __builtin_amdgcn_mfma_f32_16x16x32_bf16(af[m], bw[n], acc[m][n], 0, 0, 0);
        }
        __syncthreads();
    }
    int fr = lane & 15, fq = lane >> 4;
    #pragma unroll
    for (int m = 0; m < 4; ++m) {
        #pragma unroll
        for (int n = 0; n < 2; ++n) {
            int e = nbase + wc * 32 + n * 16 + fr;
            float bias = ob[e];
            #pragma unroll
            for (int j = 0; j < 4; ++j) {
                int p = pbase + wr * 64 + m * 16 + fq * 4 + j;
                out[(size_t)p * NE + e] = acc[m][n][j] + bias + x[(size_t)p * NE + e];
            }
        }
    }
}

extern "C" void kernel_launch(void* const* d_in, const int* in_sizes, int n_in,
                              void* d_out, int out_size, void* d_ws, size_t ws_size,
                              hipStream_t stream)
{
    const float* x    = (const float*)d_in[0];
    const float* u_w  = (const float*)d_in[1];
    const float* u_b  = (const float*)d_in[2];
    const float* v_w  = (const float*)d_in[3];
    const float* v_b  = (const float*)d_in[4];
    const float* o_w  = (const float*)d_in[5];
    const float* o_b  = (const float*)d_in[6];
    const float* r1_pw = (const float*)d_in[7];
    const float* r1_pb = (const float*)d_in[8];
    const float* r1_lw = (const float*)d_in[9];
    const float* r1_lb = (const float*)d_in[10];
    const float* r1_ow = (const float*)d_in[11];
    const float* r1_ob = (const float*)d_in[12];
    const float* r2_pw = (const float*)d_in[13];
    const float* r2_pb = (const float*)d_in[14];
    const float* r2_lw = (const float*)d_in[15];
    const float* r2_lb = (const float*)d_in[16];
    const float* r2_ow = (const float*)d_in[17];
    const float* r2_ob = (const float*)d_in[18];
    float* out = (float*)d_out;

    // workspace layout (~67 MB)
    float* A1 = (float*)d_ws;                          // NL*ND
    float* A2 = A1 + (size_t)NL * ND;                  // NL*ND
    float* h0 = A2 + (size_t)NL * ND;                  // 2*NL*NR
    float* h1 = h0 + (size_t)2 * NL * NR;              // 2*NL*NR
    bf16* wb  = (bf16*)(h1 + (size_t)2 * NL * NR);     // 1152*192
    bf16* owb = wb + (size_t)2 * ND * NE;              // 192*576
    bf16* xbc = owb + (size_t)NE * ND;                 // NPC*NE (chunk)
    bf16* u   = xbc + (size_t)NPC * NE;                // NPC*ND (chunk)
    bf16* v   = u + (size_t)NPC * ND;                  // NPC*ND (chunk)
    bf16* t   = v + (size_t)NPC * ND;                  // NPC*ND (chunk)

    // RPE nets (both nets fused per launch; net = blockIdx>>8)
    k_rpe_pos<<<dim3(512), dim3(256), 0, stream>>>(r1_pw, r1_pb, r2_pw, r2_pb, h0);
    {
        const float* src[3] = { h0, h1, h0 };
        float* dst[3]       = { h1, h0, h1 };
        for (int i = 0; i < 3; ++i) {
            k_rpe_layer<<<dim3(512), dim3(256), 0, stream>>>(
                src[i], r1_lw + (size_t)i * NR * NR, r1_lb + (size_t)i * NR,
                        r2_lw + (size_t)i * NR * NR, r2_lb + (size_t)i * NR,
                dst[i], dst[i] + (size_t)NL * NR, NR);
        }
        k_rpe_layer<<<dim3(512), dim3(256), 0, stream>>>(
            h1, r1_ow, r1_ob, r2_ow, r2_ob, A1, A2, ND);
    }

    k_wconv<<<dim3(1296), dim3(256), 0, stream>>>(u_w, v_w, o_w, wb, owb);

    for (int b = 0; b < NB; ++b) {
        const float* xb_f = x + (size_t)b * NPC * NE;
        k_prep<<<dim3(4096), dim3(256), 0, stream>>>(xb_f, xbc);
        k_uv<<<dim3(9, 128), dim3(256), 0, stream>>>(xbc, wb, u_b, v_b, u, v);
        k_conv_w<<<dim3(18, 128), dim3(256), 0, stream>>>(v, A1, t);
        k_conv_h<<<dim3(18, 128), dim3(256), 0, stream>>>(v, A2, t, u);
        k_out<<<dim3(3, 128), dim3(256), 0, stream>>>(
            u, owb, o_b, xb_f, out + (size_t)b * NPC * NE);
    }
}

// Round 4
// 1143.820 us; speedup vs baseline: 3.6295x; 1.1908x over previous
//
#include <hip/hip_runtime.h>
#include <hip/hip_bf16.h>

typedef __hip_bfloat16 bf16;
typedef __attribute__((ext_vector_type(4))) float f32x4;
typedef __attribute__((ext_vector_type(2))) float f32x2;
typedef __attribute__((ext_vector_type(8))) __bf16 bf16x8;

constexpr int NB  = 8;    // batch
constexpr int NHH = 128;  // H
constexpr int NWW = 128;  // W
constexpr int NE  = 192;  // E
constexpr int ND  = 576;  // D1 = 3E
constexpr int NR  = 512;  // RPE hidden
constexpr int NL  = 256;  // 2n
constexpr int NP  = NB * NHH * NWW;   // 131072 pixels total
constexpr int NPC = NHH * NWW;        // 16384 pixels per batch chunk

__device__ __forceinline__ void gload16(const void* g, void* l) {
    __builtin_amdgcn_global_load_lds(
        (const __attribute__((address_space(1))) unsigned int*)g,
        (__attribute__((address_space(3))) unsigned int*)l, 16, 0, 0);
}

__device__ __forceinline__ void pk_fma(f32x2& acc, f32x2 a, f32x2 b) {
    asm volatile("v_pk_fma_f32 %0, %1, %2, %0" : "+v"(acc) : "v"(a), "v"(b));
}

// ---------------- RPE: h0 = idx*pos_w + pos_b ----------------
__global__ void k_rpe_pos(const float* __restrict__ pw1, const float* __restrict__ pb1,
                          const float* __restrict__ pw2, const float* __restrict__ pb2,
                          float* __restrict__ h)
{
    int net = blockIdx.x >> 8;
    int l   = blockIdx.x & 255;
    const float* pw = net ? pw2 : pw1;
    const float* pb = net ? pb2 : pb1;
    float idxv;
    if (l == 0 || l == 128) idxv = 0.f;
    else if (l < 128)       idxv = (float)l;
    else                    idxv = (float)(l - 256);
    float* hr = h + ((size_t)net * NL + l) * NR;
    for (int r = threadIdx.x; r < NR; r += 256)
        hr[r] = idxv * pw[r] + pb[r];
}

// ---------------- one-time RPE weight transpose ----------------
// 8 matrices: per net {lw0,lw1,lw2 (512x512), ow (576x512)} -> [512][J]
// grid (16, 18, 8), block (32, 8)
__global__ __launch_bounds__(256) void k_wt(
    const float* __restrict__ lw1, const float* __restrict__ ow1,
    const float* __restrict__ lw2, const float* __restrict__ ow2,
    float* __restrict__ wt)
{
    __shared__ float tile[32][33];
    int m = blockIdx.z, net = m >> 2, sub = m & 3;
    int J = (sub == 3) ? 576 : 512;
    const float* src = (sub == 3) ? (net ? ow2 : ow1)
                                  : (net ? lw2 : lw1) + (size_t)sub * 262144;
    float* dst = wt + (size_t)net * 1081344 + ((sub == 3) ? 786432 : sub * 262144);
    int r0 = blockIdx.x * 32, j0 = blockIdx.y * 32;
    if (j0 >= J) return;
    int tx = threadIdx.x, ty = threadIdx.y;
    #pragma unroll
    for (int d = 0; d < 4; ++d) {
        int j = j0 + ty + d * 8;
        tile[ty + d * 8][tx] = (j < J) ? src[(size_t)j * 512 + r0 + tx] : 0.f;
    }
    __syncthreads();
    #pragma unroll
    for (int d = 0; d < 4; ++d) {
        int r = r0 + ty + d * 8;
        int j = j0 + tx;
        if (j < J) dst[(size_t)r * J + j] = tile[tx][ty + d * 8];
    }
}

// ---------------- RPE layer: out = relu(srms(h)) @ Wt + b ----------------
// 2 rows per block; grid 256 (net = blk>>7), block 256. Wt is [512][outdim].
__global__ __launch_bounds__(256) void k_rpe_layer(
    const float* __restrict__ hin,
    const float* __restrict__ Wt1, const float* __restrict__ b1,
    const float* __restrict__ Wt2, const float* __restrict__ b2,
    float* __restrict__ out1, float* __restrict__ out2, int outdim)
{
    __shared__ float g[2][NR];
    __shared__ float red[256];
    int net = blockIdx.x >> 7;
    int l0  = (blockIdx.x & 127) * 2;
    const float* hr = hin + ((size_t)net * NL + l0) * NR;
    int tid = threadIdx.x;
    int row = tid >> 7, ix = tid & 127;
    const float* hh = hr + (size_t)row * NR;
    float a0 = hh[ix], a1 = hh[ix + 128], a2 = hh[ix + 256], a3 = hh[ix + 384];
    red[tid] = a0 * a0 + a1 * a1 + a2 * a2 + a3 * a3;
    __syncthreads();
    for (int off = 64; off; off >>= 1) {
        if (ix < off) red[tid] += red[tid + off];
        __syncthreads();
    }
    float sc = 1.f / (sqrtf(red[row << 7]) * 0.044194173824159216f + 1e-8f);  // d=512
    g[row][ix]       = fmaxf(a0 * sc, 0.f);
    g[row][ix + 128] = fmaxf(a1 * sc, 0.f);
    g[row][ix + 256] = fmaxf(a2 * sc, 0.f);
    g[row][ix + 384] = fmaxf(a3 * sc, 0.f);
    __syncthreads();
    const float* Wt = net ? Wt2 : Wt1;
    const float* bb = net ? b2 : b1;
    float* o0 = (net ? out2 : out1) + (size_t)l0 * outdim;
    int half = outdim >> 1;
    for (int jj = tid; jj < half; jj += 256) {
        float ax0 = 0.f, ay0 = 0.f, ax1 = 0.f, ay1 = 0.f;
        const float* wp = Wt + 2 * jj;
        #pragma unroll 8
        for (int r = 0; r < NR; ++r) {
            float2 w = *(const float2*)(wp + (size_t)r * outdim);
            float g0 = g[0][r], g1 = g[1][r];
            ax0 = fmaf(g0, w.x, ax0); ay0 = fmaf(g0, w.y, ay0);
            ax1 = fmaf(g1, w.x, ax1); ay1 = fmaf(g1, w.y, ay1);
        }
        float bx = bb[2 * jj], by = bb[2 * jj + 1];
        o0[2 * jj]              = ax0 + bx;  o0[2 * jj + 1]          = ay0 + by;
        o0[outdim + 2 * jj]     = ax1 + bx;  o0[outdim + 2 * jj + 1] = ay1 + by;
    }
}

// ---------------- fused srms + bf16 cast for one chunk ----------------
__global__ void k_prep(const float* __restrict__ x, bf16* __restrict__ xb)
{
    int p = blockIdx.x * 4 + (threadIdx.x >> 6);
    int lane = threadIdx.x & 63;
    const float* xp = x + (size_t)p * NE;
    float v0 = xp[lane], v1 = xp[lane + 64], v2 = xp[lane + 128];
    float ss = v0 * v0 + v1 * v1 + v2 * v2;
    for (int off = 32; off; off >>= 1) ss += __shfl_xor(ss, off, 64);
    float sc = 1.0f / (sqrtf(ss) * 0.07216878364870323f + 1e-8f);  // d=192
    bf16* op = xb + (size_t)p * NE;
    op[lane]       = __float2bfloat16(v0 * sc);
    op[lane + 64]  = __float2bfloat16(v1 * sc);
    op[lane + 128] = __float2bfloat16(v2 * sc);
}

// ---------------- one-time weight bf16 conversion ----------------
__global__ void k_wconv(const float* __restrict__ uw, const float* __restrict__ vw,
                        const float* __restrict__ ow,
                        bf16* __restrict__ wb, bf16* __restrict__ owb)
{
    int i = blockIdx.x * 256 + threadIdx.x;
    constexpr int S = ND * NE;  // 110592
    if (i < S)          wb[i]  = __float2bfloat16(uw[i]);
    else if (i < 2 * S) wb[i]  = __float2bfloat16(vw[i - S]);
    else                owb[i - 2 * S] = __float2bfloat16(ow[i - 2 * S]);
}

// ---------------- u,v MFMA GEMM on one chunk ----------------
// M=16384 N=1152 K=192; tile 128x128, BK=64, 4 waves. grid (9, 128)
__global__ __launch_bounds__(256) void k_uv(
    const bf16* __restrict__ xb, const bf16* __restrict__ wb,
    const float* __restrict__ ub, const float* __restrict__ vb,
    bf16* __restrict__ u, bf16* __restrict__ v)
{
    __shared__ bf16 sA[128][64];
    __shared__ bf16 sB[128][64];
    int tid = threadIdx.x;
    int wv = tid >> 6, lane = tid & 63;
    int pbase = blockIdx.y * 128;
    int nbase = blockIdx.x * 128;
    int wr = wv >> 1, wc = wv & 1;
    int lrow = lane >> 3, lcol = lane & 7;
    f32x4 acc[4][4] = {};
    for (int kk = 0; kk < 3; ++kk) {
        #pragma unroll
        for (int i = 0; i < 4; ++i) {
            int row = wv * 32 + i * 8;
            gload16((const char*)(xb + (size_t)(pbase + row + lrow) * NE + kk * 64) + lcol * 16,
                    &sA[row][0]);
            gload16((const char*)(wb + (size_t)(nbase + row + lrow) * NE + kk * 64) + lcol * 16,
                    &sB[row][0]);
        }
        asm volatile("s_waitcnt vmcnt(0)" ::: "memory");
        __syncthreads();
        #pragma unroll
        for (int k2 = 0; k2 < 2; ++k2) {
            bf16x8 af[4], bw[4];
            #pragma unroll
            for (int m = 0; m < 4; ++m)
                af[m] = *(const bf16x8*)&sA[wr * 64 + m * 16 + (lane & 15)][k2 * 32 + (lane >> 4) * 8];
            #pragma unroll
            for (int n = 0; n < 4; ++n)
                bw[n] = *(const bf16x8*)&sB[wc * 64 + n * 16 + (lane & 15)][k2 * 32 + (lane >> 4) * 8];
            #pragma unroll
            for (int m = 0; m < 4; ++m)
                #pragma unroll
                for (int n = 0; n < 4; ++n)
                    acc[m][n] = __builtin_amdgcn_mfma_f32_16x16x32_bf16(af[m], bw[n], acc[m][n], 0, 0, 0);
        }
        __syncthreads();
    }
    int fr = lane & 15, fq = lane >> 4;
    #pragma unroll
    for (int m = 0; m < 4; ++m) {
        #pragma unroll
        for (int n = 0; n < 4; ++n) {
            int jn = nbase + wc * 64 + n * 16 + fr;
            float bias = (jn < ND) ? ub[jn] : vb[jn - ND];
            #pragma unroll
            for (int j = 0; j < 4; ++j) {
                int p = pbase + wr * 64 + m * 16 + fq * 4 + j;
                float z = acc[m][n][j] + bias;
                float s = z / (1.f + __expf(-z));
                if (jn < ND) u[(size_t)p * ND + jn]        = __float2bfloat16(s);
                else         v[(size_t)p * ND + (jn - ND)] = __float2bfloat16(s);
            }
        }
    }
}

// ---------------- Toeplitz conv along W (rpe1), pk_fma channel-pairs ----------------
// t[y,x,c] = sum_s A1[(x-s)&255][c] * v[y,s,c];  grid (18, 128)
__global__ __launch_bounds__(256) void k_conv_w(
    const bf16* __restrict__ v, const float* __restrict__ A1, bf16* __restrict__ t)
{
    __shared__ float vr[128][32];
    __shared__ float Al[256][34];
    int tid = threadIdx.x;
    int cc = blockIdx.x * 32;
    int y  = blockIdx.y;
    size_t rowbase = ((size_t)y * NWW) * ND + cc;
    #pragma unroll
    for (int i = 0; i < 16; ++i) {
        int idx = i * 256 + tid;
        int s = idx >> 5, c = idx & 31;
        vr[s][c] = __bfloat162float(v[rowbase + (size_t)s * ND + c]);
    }
    #pragma unroll
    for (int i = 0; i < 32; ++i) {
        int idx = i * 256 + tid;
        int k = idx >> 5, c = idx & 31;
        Al[k][c] = A1[(size_t)k * ND + cc + c];
    }
    __syncthreads();
    int ct = (tid & 15) * 2;        // channel pair
    int xb = (tid >> 4) * 8;        // 8 outputs per thread
    f32x2 acc[8] = {};
    f32x2 wA[8];
    #pragma unroll
    for (int i = 0; i < 8; ++i) wA[i] = *(const f32x2*)&Al[(xb + i) & 255][ct];
    for (int s16 = 0; s16 < 16; ++s16) {
        #pragma unroll
        for (int ss = 0; ss < 8; ++ss) {
            int s = s16 * 8 + ss;
            f32x2 vv = *(const f32x2*)&vr[s][ct];
            #pragma unroll
            for (int i = 0; i < 8; ++i)
                pk_fma(acc[i], wA[(i - ss) & 7], vv);   // wA_log[i] = A[(xb+i-s)&255]
            wA[7 - ss] = *(const f32x2*)&Al[(xb - s - 1) & 255][ct];
        }
    }
    size_t obase = ((size_t)y * NWW + xb) * ND + cc + ct;
    #pragma unroll
    for (int i = 0; i < 8; ++i) {
        unsigned int lo = __builtin_bit_cast(unsigned short, __float2bfloat16(acc[i][0]));
        unsigned int hi = __builtin_bit_cast(unsigned short, __float2bfloat16(acc[i][1]));
        *(unsigned int*)(t + obase + (size_t)i * ND) = lo | (hi << 16);
    }
}

// ---------------- Toeplitz conv along H (rpe2) + combine ----------------
// u[y,x,c] <- u * ( t + sum_s A2[(y-s)&255][c] * v[s,x,c] );  grid (18, 128)
__global__ __launch_bounds__(256) void k_conv_h(
    const bf16* __restrict__ v, const float* __restrict__ A2,
    const bf16* __restrict__ t, bf16* __restrict__ u)
{
    __shared__ float vc[128][32];
    __shared__ float Al[256][34];
    int tid = threadIdx.x;
    int cc = blockIdx.x * 32;
    int xx = blockIdx.y;
    #pragma unroll
    for (int i = 0; i < 16; ++i) {
        int idx = i * 256 + tid;
        int s = idx >> 5, c = idx & 31;
        vc[s][c] = __bfloat162float(v[((size_t)s * NWW + xx) * ND + cc + c]);
    }
    #pragma unroll
    for (int i = 0; i < 32; ++i) {
        int idx = i * 256 + tid;
        int k = idx >> 5, c = idx & 31;
        Al[k][c] = A2[(size_t)k * ND + cc + c];
    }
    __syncthreads();
    int ct = (tid & 15) * 2;
    int yb = (tid >> 4) * 8;
    f32x2 acc[8] = {};
    f32x2 wA[8];
    #pragma unroll
    for (int i = 0; i < 8; ++i) wA[i] = *(const f32x2*)&Al[(yb + i) & 255][ct];
    for (int s16 = 0; s16 < 16; ++s16) {
        #pragma unroll
        for (int ss = 0; ss < 8; ++ss) {
            int s = s16 * 8 + ss;
            f32x2 vv = *(const f32x2*)&vc[s][ct];
            #pragma unroll
            for (int i = 0; i < 8; ++i)
                pk_fma(acc[i], wA[(i - ss) & 7], vv);
            wA[7 - ss] = *(const f32x2*)&Al[(yb - s - 1) & 255][ct];
        }
    }
    #pragma unroll
    for (int i = 0; i < 8; ++i) {
        size_t p = ((size_t)(yb + i) * NWW + xx) * ND + cc + ct;
        unsigned int tu = *(const unsigned int*)(t + p);
        unsigned int uu = *(const unsigned int*)(u + p);
        float t0 = __builtin_bit_cast(float, tu << 16);
        float t1 = __builtin_bit_cast(float, tu & 0xffff0000u);
        float u0 = __builtin_bit_cast(float, uu << 16);
        float u1 = __builtin_bit_cast(float, uu & 0xffff0000u);
        float g0 = u0 * (t0 + acc[i][0]);
        float g1 = u1 * (t1 + acc[i][1]);
        unsigned int lo = __builtin_bit_cast(unsigned short, __float2bfloat16(g0));
        unsigned int hi = __builtin_bit_cast(unsigned short, __float2bfloat16(g1));
        *(unsigned int*)(u + p) = lo | (hi << 16);
    }
}

// ---------------- final MFMA GEMM: out = g @ owb^T + ob + x ----------------
// M=16384 N=192 K=576; tile 128x64, BK=64, 4 waves. grid (3, 128)
__global__ __launch_bounds__(256) void k_out(
    const bf16* __restrict__ g, const bf16* __restrict__ owb,
    const float* __restrict__ ob, const float* __restrict__ x, float* __restrict__ out)
{
    __shared__ bf16 sA[128][64];
    __shared__ bf16 sB[64][64];
    int tid = threadIdx.x;
    int wv = tid >> 6, lane = tid & 63;
    int pbase = blockIdx.y * 128;
    int nbase = blockIdx.x * 64;
    int wr = wv >> 1, wc = wv & 1;
    int lrow = lane >> 3, lcol = lane & 7;
    f32x4 acc[4][2] = {};
    for (int kk = 0; kk < 9; ++kk) {
        #pragma unroll
        for (int i = 0; i < 4; ++i) {
            int row = wv * 32 + i * 8;
            gload16((const char*)(g + (size_t)(pbase + row + lrow) * ND + kk * 64) + lcol * 16,
                    &sA[row][0]);
        }
        #pragma unroll
        for (int i = 0; i < 2; ++i) {
            int row = wv * 16 + i * 8;
            gload16((const char*)(owb + (size_t)(nbase + row + lrow) * ND + kk * 64) + lcol * 16,
                    &sB[row][0]);
        }
        asm volatile("s_waitcnt vmcnt(0)" ::: "memory");
        __syncthreads();
        #pragma unroll
        for (int k2 = 0; k2 < 2; ++k2) {
            bf16x8 af[4], bw[2];
            #pragma unroll
            for (int m = 0; m < 4; ++m)
                af[m] = *(const bf16x8*)&sA[wr * 64 + m * 16 + (lane & 15)][k2 * 32 + (lane >> 4) * 8];
            #pragma unroll
            for (int n = 0; n < 2; ++n)
                bw[n] = *(const bf16x8*)&sB[wc * 32 + n * 16 + (lane & 15)][k2 * 32 + (lane >> 4) * 8];
            #pragma unroll
            for (int m = 0; m < 4; ++m)
                #pragma unroll
                for (int n = 0; n < 2; ++n)
                    acc[m][n] = __builtin_amdgcn_mfma_f32_16x16x32_bf16(af[m], bw[n], acc[m][n], 0, 0, 0);
        }
        __syncthreads();
    }
    int fr = lane & 15, fq = lane >> 4;
    #pragma unroll
    for (int m = 0; m < 4; ++m) {
        #pragma unroll
        for (int n = 0; n < 2; ++n) {
            int e = nbase + wc * 32 + n * 16 + fr;
            float bias = ob[e];
            #pragma unroll
            for (int j = 0; j < 4; ++j) {
                int p = pbase + wr * 64 + m * 16 + fq * 4 + j;
                out[(size_t)p * NE + e] = acc[m][n][j] + bias + x[(size_t)p * NE + e];
            }
        }
    }
}

extern "C" void kernel_launch(void* const* d_in, const int* in_sizes, int n_in,
                              void* d_out, int out_size, void* d_ws, size_t ws_size,
                              hipStream_t stream)
{
    const float* x    = (const float*)d_in[0];
    const float* u_w  = (const float*)d_in[1];
    const float* u_b  = (const float*)d_in[2];
    const float* v_w  = (const float*)d_in[3];
    const float* v_b  = (const float*)d_in[4];
    const float* o_w  = (const float*)d_in[5];
    const float* o_b  = (const float*)d_in[6];
    const float* r1_pw = (const float*)d_in[7];
    const float* r1_pb = (const float*)d_in[8];
    const float* r1_lw = (const float*)d_in[9];
    const float* r1_lb = (const float*)d_in[10];
    const float* r1_ow = (const float*)d_in[11];
    const float* r1_ob = (const float*)d_in[12];
    const float* r2_pw = (const float*)d_in[13];
    const float* r2_pb = (const float*)d_in[14];
    const float* r2_lw = (const float*)d_in[15];
    const float* r2_lb = (const float*)d_in[16];
    const float* r2_ow = (const float*)d_in[17];
    const float* r2_ob = (const float*)d_in[18];
    float* out = (float*)d_out;

    // workspace layout (~76 MB)
    float* A1 = (float*)d_ws;                          // NL*ND
    float* A2 = A1 + (size_t)NL * ND;                  // NL*ND
    float* h0 = A2 + (size_t)NL * ND;                  // 2*NL*NR
    float* h1 = h0 + (size_t)2 * NL * NR;              // 2*NL*NR
    float* wt = h1 + (size_t)2 * NL * NR;              // 2*1081344 (transposed rpe W)
    bf16* wb  = (bf16*)(wt + (size_t)2 * 1081344);     // 1152*192
    bf16* owb = wb + (size_t)2 * ND * NE;              // 192*576
    bf16* xbc = owb + (size_t)NE * ND;                 // NPC*NE (chunk)
    bf16* u   = xbc + (size_t)NPC * NE;                // NPC*ND (chunk)
    bf16* v   = u + (size_t)NPC * ND;                  // NPC*ND (chunk)
    bf16* t   = v + (size_t)NPC * ND;                  // NPC*ND (chunk)

    k_rpe_pos<<<dim3(512), dim3(256), 0, stream>>>(r1_pw, r1_pb, r2_pw, r2_pb, h0);
    k_wt<<<dim3(16, 18, 8), dim3(32, 8), 0, stream>>>(r1_lw, r1_ow, r2_lw, r2_ow, wt);
    {
        // transposed weight offsets: per net stride 1081344; lw_i at i*262144; ow at 786432
        const float* src[3] = { h0, h1, h0 };
        float* dst[3]       = { h1, h0, h1 };
        for (int i = 0; i < 3; ++i) {
            k_rpe_layer<<<dim3(256), dim3(256), 0, stream>>>(
                src[i], wt + (size_t)i * 262144, r1_lb + (size_t)i * NR,
                        wt + 1081344 + (size_t)i * 262144, r2_lb + (size_t)i * NR,
                dst[i], dst[i] + (size_t)NL * NR, NR);
        }
        k_rpe_layer<<<dim3(256), dim3(256), 0, stream>>>(
            h1, wt + 786432, r1_ob, wt + 1081344 + 786432, r2_ob, A1, A2, ND);
    }

    k_wconv<<<dim3(1296), dim3(256), 0, stream>>>(u_w, v_w, o_w, wb, owb);

    for (int b = 0; b < NB; ++b) {
        const float* xb_f = x + (size_t)b * NPC * NE;
        k_prep<<<dim3(4096), dim3(256), 0, stream>>>(xb_f, xbc);
        k_uv<<<dim3(9, 128), dim3(256), 0, stream>>>(xbc, wb, u_b, v_b, u, v);
        k_conv_w<<<dim3(18, 128), dim3(256), 0, stream>>>(v, A1, t);
        k_conv_h<<<dim3(18, 128), dim3(256), 0, stream>>>(v, A2, t, u);
        k_out<<<dim3(3, 128), dim3(256), 0, stream>>>(
            u, owb, o_b, xb_f, out + (size_t)b * NPC * NE);
    }
}

// Round 5
// 717.689 us; speedup vs baseline: 5.7846x; 1.5938x over previous
//
#include <hip/hip_runtime.h>
#include <hip/hip_bf16.h>

typedef __hip_bfloat16 bf16;
typedef __attribute__((ext_vector_type(4))) float f32x4;
typedef __attribute__((ext_vector_type(8))) __bf16 bf16x8;
typedef __attribute__((ext_vector_type(4))) __bf16 bf16x4;

constexpr int NB  = 8;    // batch
constexpr int NHH = 128;  // H
constexpr int NWW = 128;  // W
constexpr int NE  = 192;  // E
constexpr int ND  = 576;  // D1 = 3E
constexpr int NR  = 512;  // RPE hidden
constexpr int NL  = 256;  // 2n
constexpr int NP  = NB * NHH * NWW;   // 131072 pixels total
constexpr int NPC = NHH * NWW;        // 16384 pixels per batch chunk

__device__ __forceinline__ void gload16(const void* g, void* l) {
    __builtin_amdgcn_global_load_lds(
        (const __attribute__((address_space(1))) unsigned int*)g,
        (__attribute__((address_space(3))) unsigned int*)l, 16, 0, 0);
}

// ---------------- RPE: h0 = idx*pos_w + pos_b ----------------
__global__ void k_rpe_pos(const float* __restrict__ pw1, const float* __restrict__ pb1,
                          const float* __restrict__ pw2, const float* __restrict__ pb2,
                          float* __restrict__ h)
{
    int net = blockIdx.x >> 8;
    int l   = blockIdx.x & 255;
    const float* pw = net ? pw2 : pw1;
    const float* pb = net ? pb2 : pb1;
    float idxv;
    if (l == 0 || l == 128) idxv = 0.f;
    else if (l < 128)       idxv = (float)l;
    else                    idxv = (float)(l - 256);
    float* hr = h + ((size_t)net * NL + l) * NR;
    for (int r = threadIdx.x; r < NR; r += 256)
        hr[r] = idxv * pw[r] + pb[r];
}

// ---------------- one-time RPE weight transpose ----------------
__global__ __launch_bounds__(256) void k_wt(
    const float* __restrict__ lw1, const float* __restrict__ ow1,
    const float* __restrict__ lw2, const float* __restrict__ ow2,
    float* __restrict__ wt)
{
    __shared__ float tile[32][33];
    int m = blockIdx.z, net = m >> 2, sub = m & 3;
    int J = (sub == 3) ? 576 : 512;
    const float* src = (sub == 3) ? (net ? ow2 : ow1)
                                  : (net ? lw2 : lw1) + (size_t)sub * 262144;
    float* dst = wt + (size_t)net * 1081344 + ((sub == 3) ? 786432 : sub * 262144);
    int r0 = blockIdx.x * 32, j0 = blockIdx.y * 32;
    if (j0 >= J) return;
    int tx = threadIdx.x, ty = threadIdx.y;
    #pragma unroll
    for (int d = 0; d < 4; ++d) {
        int j = j0 + ty + d * 8;
        tile[ty + d * 8][tx] = (j < J) ? src[(size_t)j * 512 + r0 + tx] : 0.f;
    }
    __syncthreads();
    #pragma unroll
    for (int d = 0; d < 4; ++d) {
        int r = r0 + ty + d * 8;
        int j = j0 + tx;
        if (j < J) dst[(size_t)r * J + j] = tile[tx][ty + d * 8];
    }
}

// ---------------- RPE layer: out = relu(srms(h)) @ Wt + b ----------------
__global__ __launch_bounds__(256) void k_rpe_layer(
    const float* __restrict__ hin,
    const float* __restrict__ Wt1, const float* __restrict__ b1,
    const float* __restrict__ Wt2, const float* __restrict__ b2,
    float* __restrict__ out1, float* __restrict__ out2, int outdim)
{
    __shared__ float g[2][NR];
    __shared__ float red[256];
    int net = blockIdx.x >> 7;
    int l0  = (blockIdx.x & 127) * 2;
    const float* hr = hin + ((size_t)net * NL + l0) * NR;
    int tid = threadIdx.x;
    int row = tid >> 7, ix = tid & 127;
    const float* hh = hr + (size_t)row * NR;
    float a0 = hh[ix], a1 = hh[ix + 128], a2 = hh[ix + 256], a3 = hh[ix + 384];
    red[tid] = a0 * a0 + a1 * a1 + a2 * a2 + a3 * a3;
    __syncthreads();
    for (int off = 64; off; off >>= 1) {
        if (ix < off) red[tid] += red[tid + off];
        __syncthreads();
    }
    float sc = 1.f / (sqrtf(red[row << 7]) * 0.044194173824159216f + 1e-8f);  // d=512
    g[row][ix]       = fmaxf(a0 * sc, 0.f);
    g[row][ix + 128] = fmaxf(a1 * sc, 0.f);
    g[row][ix + 256] = fmaxf(a2 * sc, 0.f);
    g[row][ix + 384] = fmaxf(a3 * sc, 0.f);
    __syncthreads();
    const float* Wt = net ? Wt2 : Wt1;
    const float* bb = net ? b2 : b1;
    float* o0 = (net ? out2 : out1) + (size_t)l0 * outdim;
    int half = outdim >> 1;
    for (int jj = tid; jj < half; jj += 256) {
        float ax0 = 0.f, ay0 = 0.f, ax1 = 0.f, ay1 = 0.f;
        const float* wp = Wt + 2 * jj;
        #pragma unroll 8
        for (int r = 0; r < NR; ++r) {
            float2 w = *(const float2*)(wp + (size_t)r * outdim);
            float g0 = g[0][r], g1 = g[1][r];
            ax0 = fmaf(g0, w.x, ax0); ay0 = fmaf(g0, w.y, ay0);
            ax1 = fmaf(g1, w.x, ax1); ay1 = fmaf(g1, w.y, ay1);
        }
        float bx = bb[2 * jj], by = bb[2 * jj + 1];
        o0[2 * jj]              = ax0 + bx;  o0[2 * jj + 1]          = ay0 + by;
        o0[outdim + 2 * jj]     = ax1 + bx;  o0[outdim + 2 * jj + 1] = ay1 + by;
    }
}

// ---------------- one-time Toeplitz matrix build ----------------
// T[net][c][r][s] = A_net[(r-s)&255][c]  (bf16), grid (36, 4, 2), block 256
__global__ __launch_bounds__(256) void k_toep(
    const float* __restrict__ A1, const float* __restrict__ A2, bf16* __restrict__ T)
{
    __shared__ float Als[256][17];
    int cb = blockIdx.x, rq = blockIdx.y, net = blockIdx.z;
    const float* A = net ? A2 : A1;
    int tid = threadIdx.x;
    #pragma unroll
    for (int i = 0; i < 16; ++i) {
        int el = i * 256 + tid;
        int k = el >> 4, cl = el & 15;
        Als[k][cl] = A[(size_t)k * ND + cb * 16 + cl];
    }
    __syncthreads();
    int cl = tid >> 4, sg = tid & 15;
    __bf16* Tb = (__bf16*)T + (((size_t)net * ND + cb * 16 + cl) * 128) * 128;
    for (int rr = 0; rr < 32; ++rr) {
        int r = rq * 32 + rr;
        bf16x8 o;
        #pragma unroll
        for (int j = 0; j < 8; ++j) {
            int s = sg * 8 + j;
            o[j] = (__bf16)Als[(r - s) & 255][cl];
        }
        *(bf16x8*)(Tb + (size_t)r * 128 + sg * 8) = o;
    }
}

// ---------------- fused srms + bf16 cast for one chunk ----------------
__global__ void k_prep(const float* __restrict__ x, bf16* __restrict__ xb)
{
    int p = blockIdx.x * 4 + (threadIdx.x >> 6);
    int lane = threadIdx.x & 63;
    const float* xp = x + (size_t)p * NE;
    float v0 = xp[lane], v1 = xp[lane + 64], v2 = xp[lane + 128];
    float ss = v0 * v0 + v1 * v1 + v2 * v2;
    for (int off = 32; off; off >>= 1) ss += __shfl_xor(ss, off, 64);
    float sc = 1.0f / (sqrtf(ss) * 0.07216878364870323f + 1e-8f);  // d=192
    bf16* op = xb + (size_t)p * NE;
    op[lane]       = __float2bfloat16(v0 * sc);
    op[lane + 64]  = __float2bfloat16(v1 * sc);
    op[lane + 128] = __float2bfloat16(v2 * sc);
}

// ---------------- one-time weight bf16 conversion ----------------
__global__ void k_wconv(const float* __restrict__ uw, const float* __restrict__ vw,
                        const float* __restrict__ ow,
                        bf16* __restrict__ wb, bf16* __restrict__ owb)
{
    int i = blockIdx.x * 256 + threadIdx.x;
    constexpr int S = ND * NE;  // 110592
    if (i < S)          wb[i]  = __float2bfloat16(uw[i]);
    else if (i < 2 * S) wb[i]  = __float2bfloat16(vw[i - S]);
    else                owb[i - 2 * S] = __float2bfloat16(ow[i - 2 * S]);
}

// ---------------- u,v MFMA GEMM, channel-major output ----------------
// M=16384 N=1152 K=192; tile 128x128, BK=64, 4 waves. grid (9, 128)
// epilogue: LDS transpose -> u_t[c][p], v_t[c][p]
__global__ __launch_bounds__(256) void k_uv(
    const bf16* __restrict__ xb, const bf16* __restrict__ wb,
    const float* __restrict__ ub, const float* __restrict__ vb,
    bf16* __restrict__ u_t, bf16* __restrict__ v_t, int chunk)
{
    __shared__ __align__(16) char smem[33792];
    __bf16 (*sA)[64] = (__bf16(*)[64])smem;
    __bf16 (*sB)[64] = (__bf16(*)[64])(smem + 16384);
    __bf16* ldst = (__bf16*)smem;   // [128][132] (aliases sA/sB after main loop)
    int tid = threadIdx.x;
    int wv = tid >> 6, lane = tid & 63;
    int by = blockIdx.y;
    int nbase = blockIdx.x * 128;
    int wr = wv >> 1, wc = wv & 1;
    int lrow = lane >> 3, lcol = lane & 7;
    f32x4 acc[4][4] = {};
    for (int kk = 0; kk < 3; ++kk) {
        #pragma unroll
        for (int i = 0; i < 4; ++i) {
            int row = wv * 32 + i * 8;
            gload16((const char*)(xb + (size_t)(by * 128 + row + lrow) * NE + kk * 64) + lcol * 16,
                    &sA[row][0]);
            gload16((const char*)(wb + (size_t)(nbase + row + lrow) * NE + kk * 64) + lcol * 16,
                    &sB[row][0]);
        }
        asm volatile("s_waitcnt vmcnt(0)" ::: "memory");
        __syncthreads();
        #pragma unroll
        for (int k2 = 0; k2 < 2; ++k2) {
            bf16x8 af[4], bw[4];
            #pragma unroll
            for (int m = 0; m < 4; ++m)
                af[m] = *(const bf16x8*)&sA[wr * 64 + m * 16 + (lane & 15)][k2 * 32 + (lane >> 4) * 8];
            #pragma unroll
            for (int n = 0; n < 4; ++n)
                bw[n] = *(const bf16x8*)&sB[wc * 64 + n * 16 + (lane & 15)][k2 * 32 + (lane >> 4) * 8];
            #pragma unroll
            for (int m = 0; m < 4; ++m)
                #pragma unroll
                for (int n = 0; n < 4; ++n)
                    acc[m][n] = __builtin_amdgcn_mfma_f32_16x16x32_bf16(af[m], bw[n], acc[m][n], 0, 0, 0);
        }
        __syncthreads();
    }
    // ---- transposed epilogue: silu+bias, stage [jn][p] in LDS, write channel-major ----
    int fr = lane & 15, fq = lane >> 4;
    #pragma unroll
    for (int m = 0; m < 4; ++m) {
        #pragma unroll
        for (int n = 0; n < 4; ++n) {
            int jn_l = wc * 64 + n * 16 + fr;
            int jn_g = nbase + jn_l;
            float bias = (jn_g < ND) ? ub[jn_g] : vb[jn_g - ND];
            bf16x4 val;
            #pragma unroll
            for (int j = 0; j < 4; ++j) {
                float z = acc[m][n][j] + bias;
                float s = z / (1.f + __expf(-z));
                val[j] = (__bf16)s;
            }
            *(bf16x4*)&ldst[jn_l * 132 + wr * 64 + m * 16 + fq * 4] = val;
        }
    }
    __syncthreads();
    size_t pgl = (size_t)chunk * NPC + (size_t)by * 128 + (tid & 15) * 8;
    #pragma unroll
    for (int pass = 0; pass < 8; ++pass) {
        int row = (tid >> 4) + pass * 16;
        int jn_g = nbase + row;
        int colb = (tid & 15) * 8;
        bf16x4 a = *(bf16x4*)&ldst[row * 132 + colb];
        bf16x4 b = *(bf16x4*)&ldst[row * 132 + colb + 4];
        bf16x8 o;
        #pragma unroll
        for (int i = 0; i < 4; ++i) { o[i] = a[i]; o[i + 4] = b[i]; }
        __bf16* dst = (jn_g < ND) ? (__bf16*)u_t + (size_t)jn_g * NP + pgl
                                  : (__bf16*)v_t + (size_t)(jn_g - ND) * NP + pgl;
        *(bf16x8*)dst = o;
    }
}

// ---------------- fused MFMA Toeplitz conv (W + H) + gate ----------------
// per (chunk, channel): G = V.T1^T + T2.V ; v_t <- u_t * G  (in place)
// grid (8, 576): x = chunk (fastest, T_c L2-reuse), y = channel
__global__ __launch_bounds__(256) void k_conv(
    bf16* __restrict__ v_t, const bf16* __restrict__ T, const bf16* __restrict__ u_t)
{
    __shared__ __bf16 Vp[128][132];
    int tid = threadIdx.x;
    int chunk = blockIdx.x, c = blockIdx.y;
    size_t pbase = (size_t)c * NP + (size_t)chunk * NPC;
    const __bf16* vsrc = (const __bf16*)v_t + pbase;
    // stage V_c (128x128) into padded LDS
    #pragma unroll
    for (int it = 0; it < 8; ++it) {
        int y = (tid >> 4) + 16 * it;
        int x0 = (tid & 15) * 8;
        bf16x8 rd = *(const bf16x8*)(vsrc + (size_t)y * 128 + x0);
        bf16x4 lo, hi;
        #pragma unroll
        for (int i = 0; i < 4; ++i) { lo[i] = rd[i]; hi[i] = rd[i + 4]; }
        *(bf16x4*)&Vp[y][x0]     = lo;
        *(bf16x4*)&Vp[y][x0 + 4] = hi;
    }
    __syncthreads();
    int wv = tid >> 6, lane = tid & 63;
    int wr = wv >> 1, wc = wv & 1;
    int fr = lane & 15, q = lane >> 4;
    const __bf16* T1 = (const __bf16*)T + (size_t)c * 16384;
    const __bf16* T2 = (const __bf16*)T + (size_t)(ND + c) * 16384;
    f32x4 acc[4][4] = {};
    // conv-W: acc[y][x] += sum_s V[y][s] * T1[x][s]
    #pragma unroll
    for (int k = 0; k < 4; ++k) {
        bf16x8 af[4], bw[4];
        #pragma unroll
        for (int m = 0; m < 4; ++m) {
            int row = wr * 64 + m * 16 + fr;
            bf16x4 a = *(const bf16x4*)&Vp[row][k * 32 + q * 8];
            bf16x4 b = *(const bf16x4*)&Vp[row][k * 32 + q * 8 + 4];
            #pragma unroll
            for (int i = 0; i < 4; ++i) { af[m][i] = a[i]; af[m][i + 4] = b[i]; }
        }
        #pragma unroll
        for (int n = 0; n < 4; ++n)
            bw[n] = *(const bf16x8*)(T1 + (size_t)(wc * 64 + n * 16 + fr) * 128 + k * 32 + q * 8);
        #pragma unroll
        for (int m = 0; m < 4; ++m)
            #pragma unroll
            for (int n = 0; n < 4; ++n)
                acc[m][n] = __builtin_amdgcn_mfma_f32_16x16x32_bf16(af[m], bw[n], acc[m][n], 0, 0, 0);
    }
    // conv-H: acc[y][x] += sum_s T2[y][s] * V[s][x]
    #pragma unroll
    for (int k = 0; k < 4; ++k) {
        bf16x8 a2[4], b2[4];
        #pragma unroll
        for (int m = 0; m < 4; ++m)
            a2[m] = *(const bf16x8*)(T2 + (size_t)(wr * 64 + m * 16 + fr) * 128 + k * 32 + q * 8);
        #pragma unroll
        for (int n = 0; n < 4; ++n) {
            int xc = wc * 64 + n * 16 + fr;
            #pragma unroll
            for (int j = 0; j < 8; ++j)
                b2[n][j] = Vp[k * 32 + q * 8 + j][xc];
        }
        #pragma unroll
        for (int m = 0; m < 4; ++m)
            #pragma unroll
            for (int n = 0; n < 4; ++n)
                acc[m][n] = __builtin_amdgcn_mfma_f32_16x16x32_bf16(a2[m], b2[n], acc[m][n], 0, 0, 0);
    }
    // epilogue: g = u * (t1+t2), overwrite v_t
    const bf16* ut = (const bf16*)u_t;
    #pragma unroll
    for (int m = 0; m < 4; ++m) {
        #pragma unroll
        for (int n = 0; n < 4; ++n) {
            int xc = wc * 64 + n * 16 + fr;
            #pragma unroll
            for (int j = 0; j < 4; ++j) {
                int y = wr * 64 + m * 16 + q * 4 + j;
                size_t p = pbase + (size_t)y * 128 + xc;
                float gv = __bfloat162float(ut[p]) * acc[m][n][j];
                ((bf16*)v_t)[p] = __float2bfloat16(gv);
            }
        }
    }
}

// ---------------- final MFMA GEMM from channel-major g ----------------
// out[p][e] = sum_c g_t[c][p]*ow[e][c] + ob[e] + x[p][e]; grid (1024)
__global__ __launch_bounds__(256) void k_out(
    const bf16* __restrict__ g_t, const bf16* __restrict__ owb,
    const float* __restrict__ ob, const float* __restrict__ x, float* __restrict__ out)
{
    __shared__ __bf16 gs[64][132];
    int tid = threadIdx.x;
    int pt = blockIdx.x;
    int wv = tid >> 6, lane = tid & 63;
    int wr = wv >> 1, wc = wv & 1;
    int fr = lane & 15, q = lane >> 4;
    f32x4 acc[4][6] = {};
    for (int kk = 0; kk < 9; ++kk) {
        // stage 64 c-rows x 128 p (reg -> padded LDS)
        #pragma unroll
        for (int i = 0; i < 4; ++i) {
            int cl = (tid >> 4) + 16 * i;
            int pg = (tid & 15) * 8;
            bf16x8 rd = *(const bf16x8*)((const __bf16*)g_t + (size_t)(kk * 64 + cl) * NP
                                         + (size_t)pt * 128 + pg);
            bf16x4 lo, hi;
            #pragma unroll
            for (int ii = 0; ii < 4; ++ii) { lo[ii] = rd[ii]; hi[ii] = rd[ii + 4]; }
            *(bf16x4*)&gs[cl][pg]     = lo;
            *(bf16x4*)&gs[cl][pg + 4] = hi;
        }
        __syncthreads();
        #pragma unroll
        for (int ks = 0; ks < 2; ++ks) {
            bf16x8 af[4], bw[6];
            #pragma unroll
            for (int m = 0; m < 4; ++m) {
                int prow = wr * 64 + m * 16 + fr;
                #pragma unroll
                for (int j = 0; j < 8; ++j)
                    af[m][j] = gs[ks * 32 + q * 8 + j][prow];
            }
            #pragma unroll
            for (int n = 0; n < 6; ++n) {
                int e = wc * 96 + n * 16 + fr;
                bw[n] = *(const bf16x8*)((const __bf16*)owb + (size_t)e * ND + kk * 64 + ks * 32 + q * 8);
            }
            #pragma unroll
            for (int m = 0; m < 4; ++m)
                #pragma unroll
                for (int n = 0; n < 6; ++n)
                    acc[m][n] = __builtin_amdgcn_mfma_f32_16x16x32_bf16(af[m], bw[n], acc[m][n], 0, 0, 0);
        }
        __syncthreads();
    }
    #pragma unroll
    for (int m = 0; m < 4; ++m) {
        #pragma unroll
        for (int n = 0; n < 6; ++n) {
            int e = wc * 96 + n * 16 + fr;
            float bias = ob[e];
            #pragma unroll
            for (int j = 0; j < 4; ++j) {
                size_t p = (size_t)pt * 128 + wr * 64 + m * 16 + q * 4 + j;
                out[p * NE + e] = acc[m][n][j] + bias + x[p * NE + e];
            }
        }
    }
}

extern "C" void kernel_launch(void* const* d_in, const int* in_sizes, int n_in,
                              void* d_out, int out_size, void* d_ws, size_t ws_size,
                              hipStream_t stream)
{
    const float* x    = (const float*)d_in[0];
    const float* u_w  = (const float*)d_in[1];
    const float* u_b  = (const float*)d_in[2];
    const float* v_w  = (const float*)d_in[3];
    const float* v_b  = (const float*)d_in[4];
    const float* o_w  = (const float*)d_in[5];
    const float* o_b  = (const float*)d_in[6];
    const float* r1_pw = (const float*)d_in[7];
    const float* r1_pb = (const float*)d_in[8];
    const float* r1_lw = (const float*)d_in[9];
    const float* r1_lb = (const float*)d_in[10];
    const float* r1_ow = (const float*)d_in[11];
    const float* r1_ob = (const float*)d_in[12];
    const float* r2_pw = (const float*)d_in[13];
    const float* r2_pb = (const float*)d_in[14];
    const float* r2_lw = (const float*)d_in[15];
    const float* r2_lb = (const float*)d_in[16];
    const float* r2_ow = (const float*)d_in[17];
    const float* r2_ob = (const float*)d_in[18];
    float* out = (float*)d_out;

    // workspace (~359 MB)
    float* A1 = (float*)d_ws;                          // NL*ND
    float* A2 = A1 + (size_t)NL * ND;                  // NL*ND
    float* h0 = A2 + (size_t)NL * ND;                  // 2*NL*NR
    float* h1 = h0 + (size_t)2 * NL * NR;              // 2*NL*NR
    float* wt = h1 + (size_t)2 * NL * NR;              // 2*1081344
    bf16* T   = (bf16*)(wt + (size_t)2 * 1081344);     // 2*576*16384
    bf16* u_t = T + (size_t)2 * ND * NPC;              // 576*131072
    bf16* v_t = u_t + (size_t)ND * NP;                 // 576*131072
    bf16* wb  = v_t + (size_t)ND * NP;                 // 1152*192
    bf16* owb = wb + (size_t)2 * ND * NE;              // 192*576
    bf16* xbc = owb + (size_t)NE * ND;                 // NPC*NE (chunk)

    k_rpe_pos<<<dim3(512), dim3(256), 0, stream>>>(r1_pw, r1_pb, r2_pw, r2_pb, h0);
    k_wt<<<dim3(16, 18, 8), dim3(32, 8), 0, stream>>>(r1_lw, r1_ow, r2_lw, r2_ow, wt);
    {
        const float* src[3] = { h0, h1, h0 };
        float* dst[3]       = { h1, h0, h1 };
        for (int i = 0; i < 3; ++i) {
            k_rpe_layer<<<dim3(256), dim3(256), 0, stream>>>(
                src[i], wt + (size_t)i * 262144, r1_lb + (size_t)i * NR,
                        wt + 1081344 + (size_t)i * 262144, r2_lb + (size_t)i * NR,
                dst[i], dst[i] + (size_t)NL * NR, NR);
        }
        k_rpe_layer<<<dim3(256), dim3(256), 0, stream>>>(
            h1, wt + 786432, r1_ob, wt + 1081344 + 786432, r2_ob, A1, A2, ND);
    }
    k_toep<<<dim3(36, 4, 2), dim3(256), 0, stream>>>(A1, A2, T);
    k_wconv<<<dim3(1296), dim3(256), 0, stream>>>(u_w, v_w, o_w, wb, owb);

    for (int b = 0; b < NB; ++b) {
        const float* xb_f = x + (size_t)b * NPC * NE;
        k_prep<<<dim3(4096), dim3(256), 0, stream>>>(xb_f, xbc);
        k_uv<<<dim3(9, 128), dim3(256), 0, stream>>>(xbc, wb, u_b, v_b, u_t, v_t, b);
    }
    k_conv<<<dim3(8, 576), dim3(256), 0, stream>>>(v_t, T, u_t);
    k_out<<<dim3(1024), dim3(256), 0, stream>>>(v_t, owb, o_b, x, out);
}